// Round 1
// baseline (131.975 us; speedup 1.0000x reference)
//
#include <hip/hip_runtime.h>

// FP8 (E4M3, unpacked bits) -> FP32 (unpacked bits) converter.
// Input : n rows x 8 floats  [s, e3, e2, e1, e0, m2, m1, m0], each 0.0 or 1.0
// Output: n rows x 32 floats [s, exp[7..0], mant[22..0]], each 0.0 or 1.0
// The output bit vector is exactly the IEEE-754 binary32 encoding of the
// FP8 value reinterpreted per the reference's ripple-adder logic:
//   normal   (e!=0):          u = (s<<31) | ((e+120)<<23) | (m<<20)
//   subnorm  m=1xx:           u = (s<<31) | (120<<23) | ((m&3)<<21)
//   subnorm  m=01x:           u = (s<<31) | (119<<23) | ((m&1)<<22)
//   subnorm  m=001:           u = (s<<31) | (118<<23)
//   zero     (e==0,m==0):     u = (s<<31)
// Output element i of a row equals bit (31-i) of u.
//
// Memory-bound: 128 MiB read + 512 MiB write. 8 lanes cooperate on one row so
// each lane stores one contiguous uint4 (perfectly coalesced writes).

__global__ __launch_bounds__(256) void fp8_bits_to_fp32_bits(
    const float4* __restrict__ in,   // 2 float4 per row
    uint4* __restrict__ out,         // 8 uint4 per row
    int n4)                          // total output uint4 count = rows * 8
{
    const unsigned ONE = 0x3F800000u;  // bits of 1.0f
    int stride = gridDim.x * blockDim.x;
    for (int gid = blockIdx.x * blockDim.x + threadIdx.x; gid < n4; gid += stride) {
        int row = gid >> 3;
        int sub = gid & 7;      // which float4 of the 32-float output row

        float4 lo = in[row * 2 + 0];  // s, e3, e2, e1
        float4 hi = in[row * 2 + 1];  // e0, m2, m1, m0

        unsigned s  = lo.x > 0.5f ? 1u : 0u;
        unsigned e3 = lo.y > 0.5f ? 1u : 0u;
        unsigned e2 = lo.z > 0.5f ? 1u : 0u;
        unsigned e1 = lo.w > 0.5f ? 1u : 0u;
        unsigned e0 = hi.x > 0.5f ? 1u : 0u;
        unsigned m2 = hi.y > 0.5f ? 1u : 0u;
        unsigned m1 = hi.z > 0.5f ? 1u : 0u;
        unsigned m0 = hi.w > 0.5f ? 1u : 0u;

        unsigned e = (e3 << 3) | (e2 << 2) | (e1 << 1) | e0;
        unsigned m = (m2 << 2) | (m1 << 1) | m0;

        unsigned u;
        if (e != 0u)        u = ((e + 120u) << 23) | (m << 20);          // normal
        else if (m & 4u)    u = (120u << 23) | ((m & 3u) << 21);         // 1xx
        else if (m & 2u)    u = (119u << 23) | ((m & 1u) << 22);         // 01x
        else if (m & 1u)    u = (118u << 23);                            // 001
        else                u = 0u;                                      // zero
        u |= s << 31;

        int i0 = sub << 2;  // first output index in [0,32)
        uint4 o;
        o.x = ((u >> (31 - (i0 + 0))) & 1u) ? ONE : 0u;
        o.y = ((u >> (31 - (i0 + 1))) & 1u) ? ONE : 0u;
        o.z = ((u >> (31 - (i0 + 2))) & 1u) ? ONE : 0u;
        o.w = ((u >> (31 - (i0 + 3))) & 1u) ? ONE : 0u;
        out[gid] = o;
    }
}

extern "C" void kernel_launch(void* const* d_in, const int* in_sizes, int n_in,
                              void* d_out, int out_size, void* d_ws, size_t ws_size,
                              hipStream_t stream) {
    const float4* in = (const float4*)d_in[0];
    uint4* out = (uint4*)d_out;
    int n4 = out_size / 4;            // 33,554,432 output uint4s
    int block = 256;
    int grid = 2048;                  // grid-stride, ~64 iters/thread
    fp8_bits_to_fp32_bits<<<grid, block, 0, stream>>>(in, out, n4);
}

// Round 2
// 129.905 us; speedup vs baseline: 1.0159x; 1.0159x over previous
//
#include <hip/hip_runtime.h>

// FP8 (E4M3, unpacked bit-floats) -> FP32 (unpacked bit-floats).
// Input : n rows x 8 floats  [s, e3, e2, e1, e0, m2, m1, m0], each 0.0f or 1.0f
// Output: n rows x 32 floats = bits of the IEEE-754 binary32 encoding:
//   normal  (e!=0):       u = (s<<31) | ((e+120)<<23) | (m<<20)
//   subnorm m=1xx:        u = (s<<31) | (120<<23) | ((m&3)<<21)
//   subnorm m=01x:        u = (s<<31) | (119<<23) | ((m&1)<<22)
//   subnorm m=001:        u = (s<<31) | (118<<23)
//   zero:                 u = (s<<31)
// Output element i of a row equals bit (31-i) of u, emitted as 1.0f/0.0f.
//
// Memory-bound (128 MiB read + 512 MiB write). Layout: 8 lanes per row, each
// lane stores one contiguous 16 B chunk -> perfect per-instruction coalescing.
// v2 changes vs v1:
//  - NON-TEMPORAL stores: output stream no longer evicts the 128 MiB input
//    from Infinity Cache between graph replays -> input re-reads become L3
//    hits, HBM traffic ~= write-only.
//  - 4x unroll with loads hoisted ahead of compute (deeper MLP).
//  - Integer bit extraction (1.0f has bit 23 set) instead of float compares.

typedef unsigned int u32x4 __attribute__((ext_vector_type(4)));

__global__ __launch_bounds__(256) void fp8_bits_to_fp32_bits(
    const u32x4* __restrict__ in,   // 2 vec4 per row
    u32x4* __restrict__ out,        // 8 vec4 per row
    int n4)                         // total output vec4 count = rows * 8
{
    const unsigned ONE = 0x3F800000u;  // bits of 1.0f
    const int stride = gridDim.x * blockDim.x;
    const int gid0 = blockIdx.x * blockDim.x + threadIdx.x;

    for (int base = gid0; base < n4; base += stride * 4) {
        u32x4 lo[4], hi[4];
        bool valid[4];

        // Issue all loads first (independent -> all in flight together).
#pragma unroll
        for (int k = 0; k < 4; ++k) {
            int gid = base + k * stride;
            valid[k] = gid < n4;
            if (valid[k]) {
                int row = gid >> 3;
                lo[k] = in[row * 2 + 0];  // s, e3, e2, e1
                hi[k] = in[row * 2 + 1];  // e0, m2, m1, m0
            }
        }

#pragma unroll
        for (int k = 0; k < 4; ++k) {
            if (!valid[k]) continue;
            int gid = base + k * stride;
            int sub = gid & 7;           // which 4-float chunk of the 32

            // bit b of word w: 1.0f = 0x3F800000 -> bit 23 set.
            unsigned s31 = (lo[k].x << 8) & 0x80000000u;
            unsigned e = ((lo[k].y >> 20) & 8u) | ((lo[k].z >> 21) & 4u) |
                         ((lo[k].w >> 22) & 2u) | ((hi[k].x >> 23) & 1u);
            unsigned m = ((hi[k].y >> 21) & 4u) | ((hi[k].z >> 22) & 2u) |
                         ((hi[k].w >> 23) & 1u);

            unsigned u;
            if (e != 0u)        u = ((e + 120u) << 23) | (m << 20);   // normal
            else if (m & 4u)    u = (120u << 23) | ((m & 3u) << 21);  // 1xx
            else if (m & 2u)    u = (119u << 23) | ((m & 1u) << 22);  // 01x
            else if (m & 1u)    u = (118u << 23);                     // 001
            else                u = 0u;                               // zero
            u |= s31;

            int i0 = sub << 2;  // first of this lane's 4 output bit indices
            u32x4 o;
            o.x = ((u >> (31 - (i0 + 0))) & 1u) ? ONE : 0u;
            o.y = ((u >> (31 - (i0 + 1))) & 1u) ? ONE : 0u;
            o.z = ((u >> (31 - (i0 + 2))) & 1u) ? ONE : 0u;
            o.w = ((u >> (31 - (i0 + 3))) & 1u) ? ONE : 0u;

            __builtin_nontemporal_store(o, &out[gid]);
        }
    }
}

extern "C" void kernel_launch(void* const* d_in, const int* in_sizes, int n_in,
                              void* d_out, int out_size, void* d_ws, size_t ws_size,
                              hipStream_t stream) {
    const u32x4* in = (const u32x4*)d_in[0];
    u32x4* out = (u32x4*)d_out;
    int n4 = out_size / 4;            // 33,554,432 output vec4s
    int block = 256;
    int grid = 2048;                  // 8 blocks/CU on 256 CUs, grid-stride
    fp8_bits_to_fp32_bits<<<grid, block, 0, stream>>>(in, out, n4);
}

// Round 3
// 105.763 us; speedup vs baseline: 1.2478x; 1.2283x over previous
//
#include <hip/hip_runtime.h>

// FP8 (E4M3, unpacked bit-floats) -> FP32 (unpacked bit-floats).
// Input : n rows x 8 floats  [s, e3, e2, e1, e0, m2, m1, m0], each 0.0f or 1.0f
// Output: n rows x 32 floats = bits (MSB-first) of the IEEE-754 binary32 word:
//   normal  (e!=0):       u = (s<<31) | ((e+120)<<23) | (m<<20)
//   subnorm m=1xx:        u = (s<<31) | (120<<23) | ((m&3)<<21)
//   subnorm m=01x:        u = (s<<31) | (119<<23) | ((m&1)<<22)
//   subnorm m=001:        u = (s<<31) | (118<<23)
//   zero:                 u = (s<<31)
//
// v3: ballot-based input dedup.
// Key observation: input word i (0/1.0f) corresponds 1:1 to output chunk i
// (chunk = 16B of 4 output bit-floats): both index (row = i>>3, pos = i&7).
// So each lane loads ONE dword (perfectly coalesced, zero duplication),
// __ballot() collects the wave's 64 input bits (bit l = lane l's word != 0),
// and lane l extracts its row's byte with (mask >> (l & 56)). __brev turns
// that LSB-first byte into the packed fp8 byte [s|e3..e0|m2..m0]. Decode, then
// each lane stores its 16B output chunk (wave store = 1 KiB contiguous, NT).
// VMEM per wave-iter: was 2x1KiB loads (87.5% duplicate lanes) + 1 store;
// now 1x256B load + 1 store.

typedef unsigned int u32x4 __attribute__((ext_vector_type(4)));

__device__ __forceinline__ unsigned decode_u(unsigned packed) {
    // packed = [bit7..bit0] = [s, e3, e2, e1, e0, m2, m1, m0]
    unsigned e = (packed >> 3) & 15u;
    unsigned m = packed & 7u;
    unsigned u;
    if (e != 0u)        u = ((e + 120u) << 23) | (m << 20);   // normal
    else if (m & 4u)    u = (120u << 23) | ((m & 3u) << 21);  // subnorm 1xx
    else if (m & 2u)    u = (119u << 23) | ((m & 1u) << 22);  // subnorm 01x
    else if (m & 1u)    u = (118u << 23);                     // subnorm 001
    else                u = 0u;                               // zero
    return u | ((packed & 0x80u) << 24);                      // sign
}

__global__ __launch_bounds__(256) void fp8_bits_to_fp32_bits(
    const unsigned* __restrict__ in,   // n4 words (1.0f or 0.0f bit patterns)
    u32x4* __restrict__ out,           // n4 output chunks
    int n4)
{
    const unsigned ONE = 0x3F800000u;  // bits of 1.0f
    const int stride = gridDim.x * blockDim.x;
    const unsigned lane = threadIdx.x & 63u;
    const unsigned shamt = lane & 56u;       // (lane/8)*8: my row's byte in mask
    const int i0 = (int)((lane & 7u) << 2);  // my 4 output bit indices start

    for (int gid = blockIdx.x * blockDim.x + threadIdx.x; gid < n4;
         gid += 2 * stride) {
        int gidB = gid + stride;
        unsigned wA = in[gid];
        unsigned wB = (gidB < n4) ? in[gidB] : 0u;

        unsigned long long mA = __ballot(wA != 0u);
        unsigned long long mB = __ballot(wB != 0u);

        unsigned pA = __brev((unsigned)(mA >> shamt) & 0xFFu) >> 24;
        unsigned pB = __brev((unsigned)(mB >> shamt) & 0xFFu) >> 24;

        unsigned uA = decode_u(pA);
        unsigned uB = decode_u(pB);

        u32x4 oA;
        oA.x = ((uA >> (31 - (i0 + 0))) & 1u) ? ONE : 0u;
        oA.y = ((uA >> (31 - (i0 + 1))) & 1u) ? ONE : 0u;
        oA.z = ((uA >> (31 - (i0 + 2))) & 1u) ? ONE : 0u;
        oA.w = ((uA >> (31 - (i0 + 3))) & 1u) ? ONE : 0u;
        __builtin_nontemporal_store(oA, &out[gid]);

        if (gidB < n4) {
            u32x4 oB;
            oB.x = ((uB >> (31 - (i0 + 0))) & 1u) ? ONE : 0u;
            oB.y = ((uB >> (31 - (i0 + 1))) & 1u) ? ONE : 0u;
            oB.z = ((uB >> (31 - (i0 + 2))) & 1u) ? ONE : 0u;
            oB.w = ((uB >> (31 - (i0 + 3))) & 1u) ? ONE : 0u;
            __builtin_nontemporal_store(oB, &out[gidB]);
        }
    }
}

extern "C" void kernel_launch(void* const* d_in, const int* in_sizes, int n_in,
                              void* d_out, int out_size, void* d_ws, size_t ws_size,
                              hipStream_t stream) {
    const unsigned* in = (const unsigned*)d_in[0];  // 33,554,432 input words
    u32x4* out = (u32x4*)d_out;
    int n4 = out_size / 4;                          // 33,554,432 output chunks
    int block = 256;
    int grid = 2048;
    fp8_bits_to_fp32_bits<<<grid, block, 0, stream>>>(in, out, n4);
}